// Round 5
// baseline (3333.164 us; speedup 1.0000x reference)
//
#include <hip/hip_runtime.h>

// N=524288 rows, A=256 features, C=19 classes.
#define NROW 524288
#define NA 256
#define NC 19
#define IGN 255
// Per-block partial layout: sum[NC][NA] | sumsq[NC][NA] | count[NC]
#define SQOFF  (NC * NA)           // 4864
#define CNTOFF (2 * NC * NA)       // 9728
#define NCELL  (2 * NC * NA + NC)  // 9747
#define OUTSTRIDE (2 * NA + 1)     // 513

// ---------------------------------------------------------------------------
// Kernel 1: register-resident per-class accumulation. NO LDS in the hot loop
// (round-4 lesson: LDS float atomics cost ~200 cy/wave-instr on gfx950).
// One wave = one row x one 128-col half; lane owns 2 contiguous cols.
// Label is wave-uniform -> readfirstlane + uniform switch -> compile-time
// class index -> s[19]/q[19] float2 arrays stay in VGPRs (no scratch).
// ---------------------------------------------------------------------------
__global__ __launch_bounds__(256, 3) void k_accum(
    const float* __restrict__ feat, const int* __restrict__ lab,
    float* __restrict__ part, int rpb)
{
    __shared__ float red[NCELL];       // epilogue merge only (38988 B)
    const int t = threadIdx.x;
    const int w = t >> 6, lane = t & 63;
    const int half = w & 1;            // which 128-col half of the row
    const int wr = w >> 1;             // row-within-pair (0/1)
    const int col0 = half * 128 + lane * 2;

    float2 s[NC], q[NC];
    #pragma unroll
    for (int k = 0; k < NC; ++k) {
        s[k] = make_float2(0.f, 0.f);
        q[k] = make_float2(0.f, 0.f);
    }
    int cnt[NC];
    #pragma unroll
    for (int k = 0; k < NC; ++k) cnt[k] = 0;
    const int inc = (half == 0) ? 1 : 0;   // count each row once (not per half)

    const int r0 = blockIdx.x * rpb;
    const int r1 = min(r0 + rpb, NROW);
    const float2* __restrict__ fg = (const float2*)feat;

    #pragma unroll 4
    for (int r = r0 + wr; r < r1; r += 2) {
        int c = __builtin_amdgcn_readfirstlane(lab[r]);   // wave-uniform
        float2 v = fg[(size_t)r * 128 + half * 64 + lane]; // 512 B/wave coalesced
        switch (c) {                    // uniform branch; compile-time k inside
#define CASE_K(k) case k: \
            s[k].x += v.x; s[k].y += v.y; \
            q[k].x += v.x * v.x; q[k].y += v.y * v.y; \
            cnt[k] += inc; break;
            CASE_K(0)  CASE_K(1)  CASE_K(2)  CASE_K(3)  CASE_K(4)
            CASE_K(5)  CASE_K(6)  CASE_K(7)  CASE_K(8)  CASE_K(9)
            CASE_K(10) CASE_K(11) CASE_K(12) CASE_K(13) CASE_K(14)
            CASE_K(15) CASE_K(16) CASE_K(17) CASE_K(18)
#undef CASE_K
            default: break;             // IGN / out-of-range
        }
    }

    // ---- epilogue: merge the 4 waves' register partials via LDS ----
    if (wr == 0) {                      // waves 0,1: write own cols
        #pragma unroll
        for (int k = 0; k < NC; ++k) {
            *(float2*)&red[k * NA + col0]         = s[k];
            *(float2*)&red[SQOFF + k * NA + col0] = q[k];
        }
        if (lane == 0 && half == 0) {
            #pragma unroll
            for (int k = 0; k < NC; ++k) red[CNTOFF + k] = (float)cnt[k];
        }
    }
    __syncthreads();
    if (wr == 1) {                      // waves 2,3: read-add-write same cols
        #pragma unroll
        for (int k = 0; k < NC; ++k) {
            float2 a = *(float2*)&red[k * NA + col0];
            a.x += s[k].x; a.y += s[k].y;
            *(float2*)&red[k * NA + col0] = a;
            float2 b = *(float2*)&red[SQOFF + k * NA + col0];
            b.x += q[k].x; b.y += q[k].y;
            *(float2*)&red[SQOFF + k * NA + col0] = b;
        }
        if (lane == 0 && half == 0) {
            #pragma unroll
            for (int k = 0; k < NC; ++k) red[CNTOFF + k] += (float)cnt[k];
        }
    }
    __syncthreads();

    float* dst = part + (size_t)blockIdx.x * NCELL;
    for (int i = t; i < NCELL; i += 256) dst[i] = red[i];   // coalesced
}

// ---------------------------------------------------------------------------
// Kernel 2: reduce [B][NCELL] partials along B into [R][NCELL] slices.
// ---------------------------------------------------------------------------
__global__ void k_reduce(const float* __restrict__ part, float* __restrict__ part2,
                         int nb, int bper)
{
    int col = blockIdx.x * 256 + threadIdx.x;
    if (col >= NCELL) return;
    int b0 = blockIdx.y * bper;
    int b1 = min(b0 + bper, nb);
    float sum = 0.0f;
    const float* p = part + (size_t)b0 * NCELL + col;
    for (int b = b0; b < b1; ++b, p += NCELL) sum += *p;
    part2[(size_t)blockIdx.y * NCELL + col] = sum;
}

// ---------------------------------------------------------------------------
// Kernel 3: finish reduction, mean/var, EMA merge, pack [CoV|Mean|Amount].
// Layout is now plain [NC][NA]: idx = c*NA + a.
// ---------------------------------------------------------------------------
__global__ void k_final(const float* __restrict__ part2, int nr,
                        const float* __restrict__ Mean, const float* __restrict__ CoV,
                        const float* __restrict__ Amt, float* __restrict__ out)
{
    int c = blockIdx.x;   // 0..18
    int a = threadIdx.x;  // 0..255
    int idx = c * NA + a;
    float s = 0.0f, q = 0.0f, cnt = 0.0f;
    for (int i = 0; i < nr; ++i) {
        const float* p = part2 + (size_t)i * NCELL;
        s   += p[idx];
        q   += p[idx + SQOFF];
        cnt += p[CNTOFF + c];   // broadcast
    }
    float amt  = Amt[c];
    float cc   = fmaxf(cnt, 1.0f);
    float mean = s / cc;
    float var  = 0.0f;
    if (cnt > 0.0f) {
        double dv = ((double)q - (double)s * (double)s / (double)cnt) / (double)cnt;
        var = (float)(dv > 0.0 ? dv : 0.0);
    }
    float denom = cnt + amt;
    float w  = (denom != 0.0f) ? (cnt / denom) : 0.0f;  // NaN (0/0) -> 0
    float om = 1.0f - w;
    float mu0 = Mean[idx];
    float cv0 = CoV[idx];
    float d   = mu0 - mean;
    float ncv = cv0 * om + var * w + w * om * d * d;
    float nmu = mu0 * om + mean * w;
    out[c * OUTSTRIDE + a]      = ncv;
    out[c * OUTSTRIDE + NA + a] = nmu;
    if (a == 0) out[c * OUTSTRIDE + 2 * NA] = amt + cnt;
}

extern "C" void kernel_launch(void* const* d_in, const int* in_sizes, int n_in,
                              void* d_out, int out_size, void* d_ws, size_t ws_size,
                              hipStream_t stream)
{
    const float* feat = (const float*)d_in[0];
    const int*   lab  = (const int*)d_in[1];
    const float* Mean = (const float*)d_in[2];
    const float* CoV  = (const float*)d_in[3];
    const float* Amt  = (const float*)d_in[4];
    float* out = (float*)d_out;

    const size_t bufBytes = (size_t)NCELL * sizeof(float);
    size_t cap = ws_size / bufBytes;
    int B = 1024, R = 8;               // 4 blocks/CU x 256 CUs
    if (cap < (size_t)(B + R)) {
        if (cap >= 16) { R = 8; B = (int)cap - R; }
        else if (cap >= 2) { R = 1; B = (int)cap - 1; }
        else { R = 1; B = 1; }
    }
    if (R > B) R = B;

    float* part  = (float*)d_ws;
    float* part2 = part + (size_t)B * NCELL;
    int rpb  = (NROW + B - 1) / B;     // 512 for B=1024
    int bper = (B + R - 1) / R;

    hipLaunchKernelGGL(k_accum, dim3(B), dim3(256), 0, stream,
                       feat, lab, part, rpb);
    hipLaunchKernelGGL(k_reduce, dim3((NCELL + 255) / 256, R), dim3(256), 0, stream,
                       part, part2, B, bper);
    hipLaunchKernelGGL(k_final, dim3(NC), dim3(256), 0, stream,
                       part2, R, Mean, CoV, Amt, out);
}

// Round 6
// 758.476 us; speedup vs baseline: 4.3946x; 4.3946x over previous
//
#include <hip/hip_runtime.h>

// N=524288 rows, A=256 features, C=19 classes.
#define NROW 524288
#define NA 256
#define NC 19
#define IGN 255
// Per-block partial layout: sum[NC][NA] | sumsq[NC][NA] | count[NC]
#define SQOFF  (NC * NA)           // 4864
#define CNTOFF (2 * NC * NA)       // 9728
#define NCELL  (2 * NC * NA + NC)  // 9747
#define OUTSTRIDE (2 * NA + 1)     // 513

// ---------------------------------------------------------------------------
// Kernel 1: ballot-partitioned register accumulation.
// Round-4 lesson: LDS float atomics ~200cy/instr. Round-5 lesson: switch over
// identical bodies gets re-merged by the compiler into a runtime index ->
// scratch spill (WRITE_SIZE 6.6GB). Fix: NAMED accumulators (s0..s18,q0..q18,
// no arrays anywhere) + per-class __ballot masks so the class is a literal.
// Wave owns a 128-col half-row (float2/lane). Hot loop per row: 1 coalesced
// global_load_dwordx2 + 4 add/fma. No LDS, no atomics, no dynamic indexing.
// Counts = popcount of the ballot (free). 2-deep load pipeline inside each
// class's bit-scan loop; 12 waves/CU give the rest of the latency hiding.
// ---------------------------------------------------------------------------
#define DECL_K(k) float2 s##k = make_float2(0.f,0.f), q##k = make_float2(0.f,0.f); int n##k = 0;
#define ACC_K(k, v) { s##k.x += (v).x; s##k.y += (v).y; \
                      q##k.x += (v).x*(v).x; q##k.y += (v).y*(v).y; }
#define KCLS(k) { \
    unsigned long long m = __ballot(lc == (k)); \
    n##k += (int)__popcll(m); \
    if (m) { \
        int b = (int)__builtin_ctzll(m); m &= m - 1ull; \
        float2 v = fb[(size_t)b * 128]; \
        while (m) { \
            int b2 = (int)__builtin_ctzll(m); m &= m - 1ull; \
            float2 vn = fb[(size_t)b2 * 128];   /* issue before consuming v */ \
            ACC_K(k, v); \
            v = vn; \
        } \
        ACC_K(k, v); \
    } }

__global__ __launch_bounds__(256, 3) void k_accum(
    const float* __restrict__ feat, const int* __restrict__ lab,
    float* __restrict__ part, int rpb)
{
    __shared__ float red[2 * NC * NA];   // sum | sumsq merge buffer
    __shared__ float wc[2][NC];          // per-wave-group counts
    const int t = threadIdx.x;
    const int wave = t >> 6, lane = t & 63;
    const int half = wave & 1;           // which 128-col half of the row
    const int grp  = wave >> 1;          // batch group (0/1)

    DECL_K(0)  DECL_K(1)  DECL_K(2)  DECL_K(3)  DECL_K(4)
    DECL_K(5)  DECL_K(6)  DECL_K(7)  DECL_K(8)  DECL_K(9)
    DECL_K(10) DECL_K(11) DECL_K(12) DECL_K(13) DECL_K(14)
    DECL_K(15) DECL_K(16) DECL_K(17) DECL_K(18)

    const int r0 = blockIdx.x * rpb;
    const int r1 = min(r0 + rpb, NROW);
    const int nbatch = (r1 - r0 + 63) >> 6;
    const float2* __restrict__ feat2 = (const float2*)feat;

    for (int g = grp; g < nbatch; g += 2) {
        const int rb = r0 + g * 64;
        const int rown = rb + lane;
        const int lc = (rown < r1) ? lab[rown] : -1;   // coalesced label batch
        const float2* fb = feat2 + (size_t)rb * 128 + half * 64 + lane;
        KCLS(0)  KCLS(1)  KCLS(2)  KCLS(3)  KCLS(4)
        KCLS(5)  KCLS(6)  KCLS(7)  KCLS(8)  KCLS(9)
        KCLS(10) KCLS(11) KCLS(12) KCLS(13) KCLS(14)
        KCLS(15) KCLS(16) KCLS(17) KCLS(18)
    }

    // ---- epilogue: merge register partials (waves 0,1 write; 2,3 add) ----
    const int col0 = half * 128 + lane * 2;
#define WR_K(k) { *(float2*)&red[(k) * NA + col0] = s##k; \
                  *(float2*)&red[SQOFF + (k) * NA + col0] = q##k; }
#define ADD_K(k) { float2 a = *(float2*)&red[(k) * NA + col0]; \
                   a.x += s##k.x; a.y += s##k.y; \
                   *(float2*)&red[(k) * NA + col0] = a; \
                   float2 b = *(float2*)&red[SQOFF + (k) * NA + col0]; \
                   b.x += q##k.x; b.y += q##k.y; \
                   *(float2*)&red[SQOFF + (k) * NA + col0] = b; }
#define WC_K(k) wc[grp][k] = (float)n##k;
    if (grp == 0) {
        WR_K(0)  WR_K(1)  WR_K(2)  WR_K(3)  WR_K(4)
        WR_K(5)  WR_K(6)  WR_K(7)  WR_K(8)  WR_K(9)
        WR_K(10) WR_K(11) WR_K(12) WR_K(13) WR_K(14)
        WR_K(15) WR_K(16) WR_K(17) WR_K(18)
    }
    if (half == 0 && lane == 0) {        // waves 0,2: counts (row counted once)
        WC_K(0)  WC_K(1)  WC_K(2)  WC_K(3)  WC_K(4)
        WC_K(5)  WC_K(6)  WC_K(7)  WC_K(8)  WC_K(9)
        WC_K(10) WC_K(11) WC_K(12) WC_K(13) WC_K(14)
        WC_K(15) WC_K(16) WC_K(17) WC_K(18)
    }
    __syncthreads();
    if (grp == 1) {
        ADD_K(0)  ADD_K(1)  ADD_K(2)  ADD_K(3)  ADD_K(4)
        ADD_K(5)  ADD_K(6)  ADD_K(7)  ADD_K(8)  ADD_K(9)
        ADD_K(10) ADD_K(11) ADD_K(12) ADD_K(13) ADD_K(14)
        ADD_K(15) ADD_K(16) ADD_K(17) ADD_K(18)
    }
    __syncthreads();

    // ---- write partials: [sum|sumsq] from red, counts from wc ----
    float* dst = part + (size_t)blockIdx.x * NCELL;
    for (int i = t; i < 2 * NC * NA; i += 256) dst[i] = red[i];   // coalesced
    if (t < NC) dst[CNTOFF + t] = wc[0][t] + wc[1][t];
}

// ---------------------------------------------------------------------------
// Kernel 2: reduce [B][NCELL] partials along B into [R][NCELL] slices.
// ---------------------------------------------------------------------------
__global__ void k_reduce(const float* __restrict__ part, float* __restrict__ part2,
                         int nb, int bper)
{
    int col = blockIdx.x * 256 + threadIdx.x;
    if (col >= NCELL) return;
    int b0 = blockIdx.y * bper;
    int b1 = min(b0 + bper, nb);
    float sum = 0.0f;
    const float* p = part + (size_t)b0 * NCELL + col;
    for (int b = b0; b < b1; ++b, p += NCELL) sum += *p;
    part2[(size_t)blockIdx.y * NCELL + col] = sum;
}

// ---------------------------------------------------------------------------
// Kernel 3: finish reduction, mean/var, EMA merge, pack [CoV|Mean|Amount].
// Layout plain [NC][NA]: idx = c*NA + a.
// ---------------------------------------------------------------------------
__global__ void k_final(const float* __restrict__ part2, int nr,
                        const float* __restrict__ Mean, const float* __restrict__ CoV,
                        const float* __restrict__ Amt, float* __restrict__ out)
{
    int c = blockIdx.x;   // 0..18
    int a = threadIdx.x;  // 0..255
    int idx = c * NA + a;
    float s = 0.0f, q = 0.0f, cnt = 0.0f;
    for (int i = 0; i < nr; ++i) {
        const float* p = part2 + (size_t)i * NCELL;
        s   += p[idx];
        q   += p[idx + SQOFF];
        cnt += p[CNTOFF + c];   // broadcast
    }
    float amt  = Amt[c];
    float cc   = fmaxf(cnt, 1.0f);
    float mean = s / cc;
    float var  = 0.0f;
    if (cnt > 0.0f) {
        double dv = ((double)q - (double)s * (double)s / (double)cnt) / (double)cnt;
        var = (float)(dv > 0.0 ? dv : 0.0);
    }
    float denom = cnt + amt;
    float w  = (denom != 0.0f) ? (cnt / denom) : 0.0f;  // NaN (0/0) -> 0
    float om = 1.0f - w;
    float mu0 = Mean[idx];
    float cv0 = CoV[idx];
    float d   = mu0 - mean;
    float ncv = cv0 * om + var * w + w * om * d * d;
    float nmu = mu0 * om + mean * w;
    out[c * OUTSTRIDE + a]      = ncv;
    out[c * OUTSTRIDE + NA + a] = nmu;
    if (a == 0) out[c * OUTSTRIDE + 2 * NA] = amt + cnt;
}

extern "C" void kernel_launch(void* const* d_in, const int* in_sizes, int n_in,
                              void* d_out, int out_size, void* d_ws, size_t ws_size,
                              hipStream_t stream)
{
    const float* feat = (const float*)d_in[0];
    const int*   lab  = (const int*)d_in[1];
    const float* Mean = (const float*)d_in[2];
    const float* CoV  = (const float*)d_in[3];
    const float* Amt  = (const float*)d_in[4];
    float* out = (float*)d_out;

    const size_t bufBytes = (size_t)NCELL * sizeof(float);
    size_t cap = ws_size / bufBytes;
    int B = 1024, R = 8;               // 4 blocks/CU x 256 CUs
    if (cap < (size_t)(B + R)) {
        if (cap >= 16) { R = 8; B = (int)cap - R; }
        else if (cap >= 2) { R = 1; B = (int)cap - 1; }
        else { R = 1; B = 1; }
    }
    if (R > B) R = B;

    float* part  = (float*)d_ws;
    float* part2 = part + (size_t)B * NCELL;
    int rpb  = (NROW + B - 1) / B;     // 512 for B=1024
    int bper = (B + R - 1) / R;

    hipLaunchKernelGGL(k_accum, dim3(B), dim3(256), 0, stream,
                       feat, lab, part, rpb);
    hipLaunchKernelGGL(k_reduce, dim3((NCELL + 255) / 256, R), dim3(256), 0, stream,
                       part, part2, B, bper);
    hipLaunchKernelGGL(k_final, dim3(NC), dim3(256), 0, stream,
                       part2, R, Mean, CoV, Amt, out);
}